// Round 6
// baseline (144.953 us; speedup 1.0000x reference)
//
#include <hip/hip_runtime.h>

// Problem constants (fixed by setup_inputs)
#define NB  8     // batch
#define SS  500   // seq
#define UU  128   // units (also GH*GD)
#define NG  5     // ngrams per chunk
#define CC  100   // chunks = S/NG
#define FF  20    // 2*C(5,2) edge-concat feature width
#define HH  5     // per-chunk heads
#define HD  10    // HH * DK (DK=2)
#define GHH 4     // graph heads
#define QT  4     // q-rows per k2 block

// ht[f] = xv[EI[f]]  (interleaved pair table, compile-time indexed)
__device__ __constant__ const int EI[FF] =
    {0,1, 0,2, 0,3, 0,4, 1,2, 1,3, 1,4, 2,3, 2,4, 3,4};

template <int CTRL>
__device__ __forceinline__ float qperm(float x) {
    return __int_as_float(__builtin_amdgcn_update_dpp(
        0, __float_as_int(x), CTRL, 0xF, 0xF, true));
}
// sum over the 4 lanes of a quad (all lanes get the result) — VALU-only DPP
__device__ __forceinline__ float quad_sum(float x) {
    x += qperm<0xB1>(x);   // quad_perm [1,0,3,2]
    x += qperm<0x4E>(x);   // quad_perm [2,3,0,1]
    return x;
}

// ---------------------------------------------------------------------------
// K1 v3: per-chunk edge MHA + leaky+mean+pos -> g (d_out)
// block = (b,c), 256 threads, ONE barrier.
//   P0: t<128 -> k+v proj for u=t; t>=128 -> q proj for u=t-128 (+ s_x stage).
//       All weight addrs wave-uniform -> scalar s_load broadcasts.
//   P1: tid = ul*4+vq; thread does u=ul and u=ul+64 over v in vq's quarter.
//       One broadcast ds_read_b128 feeds 12 VALU ops; quad reduce via DPP.
// ---------------------------------------------------------------------------
__global__ __launch_bounds__(256) void k1_chunk_mha(
    const float* __restrict__ x,   const float* __restrict__ wq,
    const float* __restrict__ bq,  const float* __restrict__ wk,
    const float* __restrict__ bk,  const float* __restrict__ wv,
    const float* __restrict__ bv,  const float* __restrict__ wo,
    const float* __restrict__ bo,  const float* __restrict__ pos,
    float* __restrict__ g_out)
{
    const int bc  = blockIdx.x;
    const int b   = bc / CC, c = bc % CC;
    const int tid = threadIdx.x;
    const int u0  = tid & 127;

    __shared__ float4 s_kv[HH][UU];   // (k0,k1,v0,v1) per (head, pos)  10 KB
    __shared__ float2 s_q[HH][UU];    // q pre-scaled by 1/sqrt(2)*log2e  5 KB
    __shared__ float  s_x[NG][UU];    // staged ngram values            2.5 KB

    // ---------------- P0 ----------------
    float xv[NG];
    const float* xb = x + (size_t)b*SS*UU + (size_t)c*NG*UU + u0;
#pragma unroll
    for (int t = 0; t < NG; ++t) xv[t] = xb[t*UU];     // coalesced

    if (tid < 128) {
        // k + v projections (interleaved for ILP); weights block-uniform
        float pk[HD], pv[HD];
        const float2* bk2 = (const float2*)(bk + c*HD);
        const float2* bv2 = (const float2*)(bv + c*HD);
#pragma unroll
        for (int d2 = 0; d2 < 5; ++d2) {
            const float2 a = bk2[d2], v2 = bv2[d2];
            pk[2*d2] = a.x;  pk[2*d2+1] = a.y;
            pv[2*d2] = v2.x; pv[2*d2+1] = v2.y;
        }
        const float2* wk2 = (const float2*)(wk + c*(FF*HD));
        const float2* wv2 = (const float2*)(wv + c*(FF*HD));
#pragma unroll
        for (int f = 0; f < FF; ++f) {
            const float hf = xv[EI[f]];
#pragma unroll
            for (int d2 = 0; d2 < 5; ++d2) {
                const float2 a = wk2[f*5+d2], v2 = wv2[f*5+d2];
                pk[2*d2]   = fmaf(hf, a.x,  pk[2*d2]);
                pk[2*d2+1] = fmaf(hf, a.y,  pk[2*d2+1]);
                pv[2*d2]   = fmaf(hf, v2.x, pv[2*d2]);
                pv[2*d2+1] = fmaf(hf, v2.y, pv[2*d2+1]);
            }
        }
#pragma unroll
        for (int h = 0; h < HH; ++h)
            s_kv[h][u0] = make_float4(pk[2*h], pk[2*h+1], pv[2*h], pv[2*h+1]);
    } else {
        float pq[HD];
        const float2* bq2 = (const float2*)(bq + c*HD);
#pragma unroll
        for (int d2 = 0; d2 < 5; ++d2) {
            const float2 a = bq2[d2];
            pq[2*d2] = a.x; pq[2*d2+1] = a.y;
        }
        const float2* wq2 = (const float2*)(wq + c*(FF*HD));
#pragma unroll
        for (int f = 0; f < FF; ++f) {
            const float hf = xv[EI[f]];
#pragma unroll
            for (int d2 = 0; d2 < 5; ++d2) {
                const float2 a = wq2[f*5+d2];
                pq[2*d2]   = fmaf(hf, a.x, pq[2*d2]);
                pq[2*d2+1] = fmaf(hf, a.y, pq[2*d2+1]);
            }
        }
        const float C = 1.0202559313584566f;  // (1/sqrt(dk=2)) * log2(e)
#pragma unroll
        for (int h = 0; h < HH; ++h)
            s_q[h][u0] = make_float2(pq[2*h]*C, pq[2*h+1]*C);
#pragma unroll
        for (int t = 0; t < NG; ++t) s_x[t][u0] = xv[t];
    }
    __syncthreads();                           // the only barrier

    // ---------------- P1: attention, 2 u's per thread ----------------
    const int ul = tid >> 2;                   // 0..63
    const int vq = tid & 3;                    // quad lane
    float qa0[HH], qa1[HH], qb0[HH], qb1[HH];
#pragma unroll
    for (int h = 0; h < HH; ++h) {
        const float2 qa = s_q[h][ul], qb = s_q[h][ul+64];
        qa0[h]=qa.x; qa1[h]=qa.y; qb0[h]=qb.x; qb1[h]=qb.y;
    }
    float la[HH], oa0[HH], oa1[HH], lb[HH], ob0[HH], ob1[HH];
#pragma unroll
    for (int h = 0; h < HH; ++h) {
        la[h]=0.f; oa0[h]=0.f; oa1[h]=0.f;
        lb[h]=0.f; ob0[h]=0.f; ob1[h]=0.f;
    }
    const int rot = 9*vq;   // offsets stay distinct mod 8 -> disjoint bank quads
#pragma unroll
    for (int h = 0; h < HH; ++h) {
#pragma unroll 8
        for (int i = 0; i < 32; ++i) {
            const int v = vq*32 + ((i + rot) & 31);
            const float4 kv = s_kv[h][v];      // 4-addr multicast, conflict-free
            const float sa = fmaf(qa0[h], kv.x, qa1[h]*kv.y);
            const float ea = __builtin_amdgcn_exp2f(sa);  // |s|<~2: exact
            la[h] += ea;
            oa0[h] = fmaf(ea, kv.z, oa0[h]);
            oa1[h] = fmaf(ea, kv.w, oa1[h]);
            const float sb = fmaf(qb0[h], kv.x, qb1[h]*kv.y);
            const float eb = __builtin_amdgcn_exp2f(sb);
            lb[h] += eb;
            ob0[h] = fmaf(eb, kv.z, ob0[h]);
            ob1[h] = fmaf(eb, kv.w, ob1[h]);
        }
    }
    // quad reduce (DPP, no LDS, no barrier)
    float oa[HD], ob[HD];
#pragma unroll
    for (int h = 0; h < HH; ++h) {
        const float La = quad_sum(la[h]), Oa0 = quad_sum(oa0[h]), Oa1 = quad_sum(oa1[h]);
        const float Lb = quad_sum(lb[h]), Ob0 = quad_sum(ob0[h]), Ob1 = quad_sum(ob1[h]);
        const float ia = 1.f/La, ib = 1.f/Lb;
        oa[2*h] = Oa0*ia; oa[2*h+1] = Oa1*ia;
        ob[2*h] = Ob0*ib; ob[2*h+1] = Ob1*ib;
    }

    // epilogue: out-proj + residual + leaky(0.3) + mean (wo/bo scalar loads;
    // 4x redundant across the quad but barrier-free)
    float xa[NG], xb2[NG];
#pragma unroll
    for (int t = 0; t < NG; ++t) { xa[t] = s_x[t][ul]; xb2[t] = s_x[t][ul+64]; }
    const float* woc = wo + c*(HD*FF);
    const float* boc = bo + c*FF;
    float ga = 0.f, gb = 0.f;
#pragma unroll
    for (int f = 0; f < FF; ++f) {
        float aa = boc[f], ab = boc[f];
#pragma unroll
        for (int hd = 0; hd < HD; ++hd) {
            const float w = woc[hd*FF + f];
            aa = fmaf(oa[hd], w, aa);
            ab = fmaf(ob[hd], w, ab);
        }
        aa += xa[EI[f]]; ab += xb2[EI[f]];
        ga += (aa > 0.f) ? aa : 0.3f*aa;
        gb += (ab > 0.f) ? ab : 0.3f*ab;
    }
    if (vq == 0) {
        g_out[(size_t)bc*UU + ul]      = ga*(1.f/FF) + pos[c*UU + ul];
        g_out[(size_t)bc*UU + ul + 64] = gb*(1.f/FF) + pos[c*UU + ul + 64];
    }
}

// ---------------------------------------------------------------------------
// K_QKV: gq/gk/gv = g @ gw* + gb*  (M=800, K=128, N=3x128), row-blocked 4x
// to amortize weight reads (38 MB total L2 traffic vs 154 MB when fused).
// 200 blocks x 384 threads; wave-uniform array select (n>>7).
// ---------------------------------------------------------------------------
__global__ __launch_bounds__(384) void k_qkv(
    const float* __restrict__ g,
    const float* __restrict__ gwq, const float* __restrict__ gbq,
    const float* __restrict__ gwk, const float* __restrict__ gbk,
    const float* __restrict__ gwv, const float* __restrict__ gbv,
    float* __restrict__ gq, float* __restrict__ gk, float* __restrict__ gv)
{
    const int r0  = blockIdx.x * 4;
    const int n   = threadIdx.x;       // 0..383
    const int arr = n >> 7;            // wave-uniform: 0=q,1=k,2=v
    const int col = n & 127;
    const float* W = (arr == 0) ? gwq : (arr == 1) ? gwk : gwv;
    const float* B = (arr == 0) ? gbq : (arr == 1) ? gbk : gbv;
    const float* grow = g + (size_t)r0 * UU;   // block-uniform -> s_load

    float a0, a1, a2, a3;
    a0 = a1 = a2 = a3 = B[col];
#pragma unroll 8
    for (int k = 0; k < UU; ++k) {
        const float w = W[k*UU + col];         // coalesced across col
        a0 = fmaf(grow[k],        w, a0);
        a1 = fmaf(grow[UU + k],   w, a1);
        a2 = fmaf(grow[2*UU + k], w, a2);
        a3 = fmaf(grow[3*UU + k], w, a3);
    }
    float* O = (arr == 0) ? gq : (arr == 1) ? gk : gv;
    const float sc = (arr == 0) ? 0.17677669529663687f : 1.f;  // 1/sqrt(32)
    O[(size_t)(r0+0)*UU + col] = a0 * sc;
    O[(size_t)(r0+1)*UU + col] = a1 * sc;
    O[(size_t)(r0+2)*UU + col] = a2 * sc;
    O[(size_t)(r0+3)*UU + col] = a3 * sc;
}

// ---------------------------------------------------------------------------
// K2 v3: graph attention + out-proj + residual, QT=4 q-rows per block
// (amortizes gk/gv/gwo reads 4x). 200 blocks x 256 threads.
// ---------------------------------------------------------------------------
__global__ __launch_bounds__(256) void k2_graph(
    const float* __restrict__ gq, const float* __restrict__ gk,
    const float* __restrict__ gv, const float* __restrict__ gwo,
    const float* __restrict__ gbo, float* __restrict__ out)
{
    const int blk = blockIdx.x;
    const int b   = blk / (CC/QT);
    const int q0  = (blk % (CC/QT)) * QT;
    const int t   = threadIdx.x;

    __shared__ float s_q[QT][UU];            // 2 KB
    __shared__ float s_e[QT][GHH][CC];       // 6.4 KB
    __shared__ float s_pa[2][QT][UU];        // 4 KB
    __shared__ float s_pl[2][QT][UU];        // 4 KB
    __shared__ float s_o[QT][UU];            // 2 KB
    __shared__ float s_p3[2][QT][UU];        // 4 KB

    // stage q rows, fold log2(e) (gq already has 1/sqrt(gd))
#pragma unroll
    for (int r = 0; r < 2; ++r) {
        const int idx = r*256 + t;
        const int qi = idx >> 7, u = idx & 127;
        s_q[qi][u] = gq[((size_t)b*CC + q0 + qi)*UU + u] * 1.4426950408889634f;
    }
    __syncthreads();

    // phase 1: scores + exp2; thread = (k, head-pair); k-row loaded once,
    // reused across the 4 q's
    {
        const int k = t & 127, hp = t >> 7;
        if (k < CC) {
            const float4* krow = (const float4*)(gk + ((size_t)b*CC + k)*UU);
#pragma unroll
            for (int hh = 0; hh < 2; ++hh) {
                const int h = hp*2 + hh;
                float4 kf[8];
#pragma unroll
                for (int i = 0; i < 8; ++i) kf[i] = krow[h*8 + i];
#pragma unroll
                for (int qi = 0; qi < QT; ++qi) {
                    const float4* q4 = (const float4*)s_q[qi];  // broadcast
                    float s = 0.f;
#pragma unroll
                    for (int i = 0; i < 8; ++i) {
                        const float4 qf = q4[h*8 + i];
                        s = fmaf(qf.x, kf[i].x, s); s = fmaf(qf.y, kf[i].y, s);
                        s = fmaf(qf.z, kf[i].z, s); s = fmaf(qf.w, kf[i].w, s);
                    }
                    s_e[qi][h][k] = __builtin_amdgcn_exp2f(s);  // tiny scores
                }
            }
        }
    }
    __syncthreads();

    // phase 2: o/l partials; thread = (d, k-half); v loaded once per k,
    // reused across the 4 q's
    {
        const int d = t & 127, kh = t >> 7, h = d >> 5;
        const float* vcol = gv + (size_t)b*CC*UU + d;
        float l[QT] = {0.f,0.f,0.f,0.f}, o[QT] = {0.f,0.f,0.f,0.f};
#pragma unroll 5
        for (int i = 0; i < 50; ++i) {
            const int k = kh*50 + i;
            const float v = vcol[(size_t)k*UU];   // coalesced across d
#pragma unroll
            for (int qi = 0; qi < QT; ++qi) {
                const float e = s_e[qi][h][k];    // 2-addr multicast: free
                l[qi] += e;
                o[qi] = fmaf(e, v, o[qi]);
            }
        }
#pragma unroll
        for (int qi = 0; qi < QT; ++qi) {
            s_pa[kh][qi][d] = o[qi]; s_pl[kh][qi][d] = l[qi];
        }
    }
    __syncthreads();
#pragma unroll
    for (int r = 0; r < 2; ++r) {
        const int idx = r*256 + t;
        const int qi = idx >> 7, d = idx & 127;
        s_o[qi][d] = (s_pa[0][qi][d] + s_pa[1][qi][d])
                   / (s_pl[0][qi][d] + s_pl[1][qi][d]);
    }
    __syncthreads();

    // phase 3: out-proj; thread = (u, hd-half); gwo loaded once per hd,
    // reused across the 4 q's
    {
        const int u = t & 127, half = t >> 7;
        float acc[QT] = {0.f,0.f,0.f,0.f};
#pragma unroll 8
        for (int i = 0; i < 64; ++i) {
            const int hd = half*64 + i;
            const float w = gwo[hd*UU + u];       // coalesced across u
#pragma unroll
            for (int qi = 0; qi < QT; ++qi)
                acc[qi] = fmaf(s_o[qi][hd], w, acc[qi]);  // broadcast reads
        }
#pragma unroll
        for (int qi = 0; qi < QT; ++qi) s_p3[half][qi][u] = acc[qi];
    }
    __syncthreads();
#pragma unroll
    for (int r = 0; r < 2; ++r) {
        const int idx = r*256 + t;
        const int qi = idx >> 7, u = idx & 127;
        const size_t row = (size_t)b*CC + q0 + qi;
        out[row*UU + u] += s_p3[0][qi][u] + s_p3[1][qi][u] + gbo[u];
    }
}

extern "C" void kernel_launch(void* const* d_in, const int* in_sizes, int n_in,
                              void* d_out, int out_size, void* d_ws, size_t ws_size,
                              hipStream_t stream)
{
    (void)in_sizes; (void)n_in; (void)out_size; (void)ws_size;
    const float* x   = (const float*)d_in[0];
    const float* wq  = (const float*)d_in[1];
    const float* bq  = (const float*)d_in[2];
    const float* wk  = (const float*)d_in[3];
    const float* bk  = (const float*)d_in[4];
    const float* wv  = (const float*)d_in[5];
    const float* bv  = (const float*)d_in[6];
    const float* wo  = (const float*)d_in[7];
    const float* bo  = (const float*)d_in[8];
    const float* pos = (const float*)d_in[9];
    const float* gwq = (const float*)d_in[10];
    const float* gbq = (const float*)d_in[11];
    const float* gwk = (const float*)d_in[12];
    const float* gbk = (const float*)d_in[13];
    const float* gwv = (const float*)d_in[14];
    const float* gbv = (const float*)d_in[15];
    const float* gwo = (const float*)d_in[16];
    const float* gbo = (const float*)d_in[17];
    float* out = (float*)d_out;
    float* ws  = (float*)d_ws;

    float* gq_ws = ws;              // [8*100*128]
    float* gk_ws = ws + 102400;
    float* gv_ws = ws + 204800;

    k1_chunk_mha<<<NB*CC, 256, 0, stream>>>(x, wq, bq, wk, bk, wv, bv, wo, bo,
                                            pos, out);
    k_qkv<<<NB*CC/4, 384, 0, stream>>>(out, gwq, gbq, gwk, gbk, gwv, gbv,
                                       gq_ws, gk_ws, gv_ws);
    k2_graph<<<NB*(CC/QT), 256, 0, stream>>>(gq_ws, gk_ws, gv_ws, gwo, gbo, out);
}

// Round 7
// 133.926 us; speedup vs baseline: 1.0823x; 1.0823x over previous
//
#include <hip/hip_runtime.h>

// Problem constants (fixed by setup_inputs)
#define NB  8     // batch
#define SS  500   // seq
#define UU  128   // units (also GH*GD)
#define NG  5     // ngrams per chunk
#define CC  100   // chunks = S/NG
#define FF  20    // 2*C(5,2) edge-concat feature width
#define HH  5     // per-chunk heads
#define HD  10    // HH * DK (DK=2)
#define GHH 4     // graph heads

// ht[f] = xv[EI[f]]  (interleaved pair table, compile-time indexed)
__device__ __constant__ const int EI[FF] =
    {0,1, 0,2, 0,3, 0,4, 1,2, 1,3, 1,4, 2,3, 2,4, 3,4};

template <int CTRL>
__device__ __forceinline__ float qperm(float x) {
    return __int_as_float(__builtin_amdgcn_update_dpp(
        0, __float_as_int(x), CTRL, 0xF, 0xF, true));
}
// sum over the 4 lanes of a quad (all lanes get the result) — VALU-only DPP
__device__ __forceinline__ float quad_sum(float x) {
    x += qperm<0xB1>(x);   // quad_perm [1,0,3,2]
    x += qperm<0x4E>(x);   // quad_perm [2,3,0,1]
    return x;
}

// qkv projection: weights block-uniform (c) -> scalar s_load broadcasts
__device__ __forceinline__ void proj10(const float* __restrict__ w,
                                       const float* __restrict__ bias,
                                       int c, const float xv[NG], float p[HD])
{
    const float2* bs2 = (const float2*)(bias + c * HD);
#pragma unroll
    for (int d2 = 0; d2 < 5; ++d2) {
        const float2 t2 = bs2[d2];
        p[2*d2] = t2.x; p[2*d2+1] = t2.y;
    }
    const float2* w2 = (const float2*)(w + c * (FF * HD));
#pragma unroll
    for (int f = 0; f < FF; ++f) {
        const float hf = xv[EI[f]];               // compile-time index
#pragma unroll
        for (int d2 = 0; d2 < 5; ++d2) {
            const float2 t2 = w2[f*5 + d2];
            p[2*d2]   = fmaf(hf, t2.x, p[2*d2]);
            p[2*d2+1] = fmaf(hf, t2.y, p[2*d2+1]);
        }
    }
}

// ---------------------------------------------------------------------------
// K1 v4: per-chunk edge MHA + leaky+mean+pos -> g (d_out), + graph qkv -> ws
// block = (b,c), 512 threads, 3 barriers, 24 KB LDS.
//  P0: grp = tid>>7 (wave-pair uniform): 0 -> q proj, 1 -> k, 2 -> v,
//      3 -> stage x into LDS. All weight addrs wave-uniform -> s_load.
//  P1: tid = u*4+vq. Thread covers u over vq's 32 v-positions (160 exp chain);
//      quad partials reduced via DPP (no LDS, no barrier). Epilogue on all
//      quad lanes (4x redundant, fills lanes, barrier-free).
//  P2/P3: graph qkv projection (u, quarter) as in R5.
// ---------------------------------------------------------------------------
__global__ __launch_bounds__(512) void k1_chunk_mha(
    const float* __restrict__ x,   const float* __restrict__ wq,
    const float* __restrict__ bq,  const float* __restrict__ wk,
    const float* __restrict__ bk,  const float* __restrict__ wv,
    const float* __restrict__ bv,  const float* __restrict__ wo,
    const float* __restrict__ bo,  const float* __restrict__ pos,
    const float* __restrict__ gwq, const float* __restrict__ gbq,
    const float* __restrict__ gwk, const float* __restrict__ gbk,
    const float* __restrict__ gwv, const float* __restrict__ gbv,
    float* __restrict__ g_out, float* __restrict__ gq_out,
    float* __restrict__ gk_out, float* __restrict__ gv_out)
{
    const int bc  = blockIdx.x;
    const int b   = bc / CC, c = bc % CC;
    const int tid = threadIdx.x;
    const int u0  = tid & 127;
    const int grp = tid >> 7;            // 0..3, uniform per wave-pair

    __shared__ float2 s_q[HH][UU];       // q pre-scaled by 1/sqrt(2)*log2e 5 KB
    __shared__ float4 s_kv[HH][UU];      // (k0,k1,v0,v1)                 10 KB
    __shared__ float  s_x[NG][UU];       // staged ngram values          2.5 KB
    __shared__ float  s_g[UU];           //                              0.5 KB
    __shared__ float  s_gr[4][3][UU];    // graph-qkv partials             6 KB

    // ---------------- P0: x load + role projection -----------------------
    float xv[NG];
    {
        const float* xb = x + (size_t)b*SS*UU + (size_t)c*NG*UU + u0;
#pragma unroll
        for (int t = 0; t < NG; ++t) xv[t] = xb[t*UU];     // coalesced
    }
    if (grp == 0) {
        float p[HD];
        proj10(wq, bq, c, xv, p);
        const float C = 1.0202559313584566f;   // (1/sqrt(dk=2)) * log2(e)
#pragma unroll
        for (int h = 0; h < HH; ++h)
            s_q[h][u0] = make_float2(p[2*h]*C, p[2*h+1]*C);
    } else if (grp == 1) {
        float p[HD];
        proj10(wk, bk, c, xv, p);
#pragma unroll
        for (int h = 0; h < HH; ++h) { s_kv[h][u0].x = p[2*h]; s_kv[h][u0].y = p[2*h+1]; }
    } else if (grp == 2) {
        float p[HD];
        proj10(wv, bv, c, xv, p);
#pragma unroll
        for (int h = 0; h < HH; ++h) { s_kv[h][u0].z = p[2*h]; s_kv[h][u0].w = p[2*h+1]; }
    } else {
#pragma unroll
        for (int t = 0; t < NG; ++t) s_x[t][u0] = xv[t];
    }
    __syncthreads();                               // B1: q/k/v/x ready

    // ---------------- P1: attention; quad owns one u ----------------------
    const int u  = tid >> 2;                       // 0..127
    const int vq = tid & 3;                        // quad lane
    float q0[HH], q1[HH];
#pragma unroll
    for (int h = 0; h < HH; ++h) {
        const float2 qq = s_q[h][u];               // 16 addrs/wave, 2-way: free
        q0[h] = qq.x; q1[h] = qq.y;
    }
    float l[HH], o0[HH], o1[HH];
#pragma unroll
    for (int h = 0; h < HH; ++h) { l[h]=0.f; o0[h]=0.f; o1[h]=0.f; }
    const int rot = 9*vq;  // 4 quad addrs distinct mod 8 -> disjoint bank quads
#pragma unroll
    for (int h = 0; h < HH; ++h) {
#pragma unroll 8
        for (int i = 0; i < 32; ++i) {
            const int v = vq*32 + ((i + rot) & 31);
            const float4 kv = s_kv[h][v];          // 4-addr multicast b128
            const float s = fmaf(q0[h], kv.x, q1[h]*kv.y);
            const float e = __builtin_amdgcn_exp2f(s);   // |s| tiny: exact
            l[h]  += e;
            o0[h]  = fmaf(e, kv.z, o0[h]);
            o1[h]  = fmaf(e, kv.w, o1[h]);
        }
    }
    // quad reduce (DPP, VALU-only) -> all 4 lanes hold full o for u
    float o[HD];
#pragma unroll
    for (int h = 0; h < HH; ++h) {
        const float L  = quad_sum(l[h]);
        const float O0 = quad_sum(o0[h]);
        const float O1 = quad_sum(o1[h]);
        const float inv = 1.f / L;
        o[2*h] = O0*inv; o[2*h+1] = O1*inv;
    }

    // epilogue on ALL lanes (4x redundant, barrier-free):
    // out-proj + residual + leaky(0.3) + mean; wo/bo block-uniform -> s_load
    float xu[NG];
#pragma unroll
    for (int t = 0; t < NG; ++t) xu[t] = s_x[t][u];  // 16 addrs, 4-way multicast
    const float* woc = wo + c*(HD*FF);
    const float* boc = bo + c*FF;
    float gsum = 0.f;
#pragma unroll
    for (int f = 0; f < FF; ++f) {
        float acc = boc[f];
#pragma unroll
        for (int hd = 0; hd < HD; ++hd) acc = fmaf(o[hd], woc[hd*FF + f], acc);
        const float a = xu[EI[f]] + acc;
        gsum += (a > 0.f) ? a : 0.3f*a;
    }
    const float g = gsum*(1.f/FF) + pos[c*UU + u];
    if (vq == 0) {
        s_g[u] = g;
        g_out[(size_t)bc*UU + u] = g;
    }
    __syncthreads();                               // B2: s_g ready

    // ---------------- P2: graph qkv partials; thread = (u0, grp-quarter) --
    float aq = 0.f, ak = 0.f, av = 0.f;
#pragma unroll 4
    for (int i = 0; i < 32; ++i) {
        const int u2 = grp*32 + i;                 // wave-uniform
        const float gu = s_g[u2];                  // broadcast
        aq = fmaf(gu, gwq[u2*UU + u0], aq);        // coalesced across u0
        ak = fmaf(gu, gwk[u2*UU + u0], ak);
        av = fmaf(gu, gwv[u2*UU + u0], av);
    }
    s_gr[grp][0][u0] = aq; s_gr[grp][1][u0] = ak; s_gr[grp][2][u0] = av;
    __syncthreads();                               // B3

    // ---------------- P3: final sums + stores -----------------------------
    if (grp < 3) {
        const float s = s_gr[0][grp][u0] + s_gr[1][grp][u0]
                      + s_gr[2][grp][u0] + s_gr[3][grp][u0];
        if (grp == 0)
            gq_out[(size_t)bc*UU + u0] = (s + gbq[u0]) * 0.17677669529663687f;
        else if (grp == 1)
            gk_out[(size_t)bc*UU + u0] = s + gbk[u0];
        else
            gv_out[(size_t)bc*UU + u0] = s + gbv[u0];
    }
}

// ---------------------------------------------------------------------------
// K2: graph attention + out-proj + residual. block=(b,q), 800 blocks x 256.
// (R5 structure — max parallelism; QT-blocking regressed in R6.)
// ---------------------------------------------------------------------------
__global__ __launch_bounds__(256) void k2_graph(
    const float* __restrict__ gq, const float* __restrict__ gk,
    const float* __restrict__ gv, const float* __restrict__ gwo,
    const float* __restrict__ gbo, float* __restrict__ out)
{
    const int bq = blockIdx.x;
    const int b  = bq / CC;
    const int t  = threadIdx.x;

    __shared__ float s_q[UU];
    __shared__ float s_e[GHH][CC];
    __shared__ float s_pa[2][UU];   // o partials
    __shared__ float s_pl[2][UU];   // l partials
    __shared__ float s_o[UU];
    __shared__ float s_p3[2][UU];

    float gval = 0.f;
    if (t < UU) {
        gval  = out[(size_t)bq*UU + t];            // g (written by K1)
        s_q[t] = gq[(size_t)bq*UU + t] * 1.4426950408889634f;  // fold log2e
    }
    __syncthreads();

    // phase 1: scores+exp2; thread = (k, head-pair)
    if (t < 200) {
        const int k  = (t < 100) ? t : t - 100;
        const int h0 = (t < 100) ? 0 : 2;
        const float4* krow = (const float4*)(gk + ((size_t)b*CC + k)*UU);
        const float4* q4   = (const float4*)s_q;   // uniform -> broadcast
#pragma unroll
        for (int hh = 0; hh < 2; ++hh) {
            const int h = h0 + hh;
            float s = 0.f;
#pragma unroll
            for (int i = 0; i < 8; ++i) {
                const float4 kf = krow[h*8 + i];
                const float4 qf = q4[h*8 + i];
                s = fmaf(qf.x, kf.x, s); s = fmaf(qf.y, kf.y, s);
                s = fmaf(qf.z, kf.z, s); s = fmaf(qf.w, kf.w, s);
            }
            s_e[h][k] = __builtin_amdgcn_exp2f(s); // scores tiny: shift-free
        }
    }
    __syncthreads();

    // phase 2: o/l partials; thread = (d, k-half)
    {
        const int d = t & 127, kh = t >> 7, h = d >> 5;
        const float* vcol = gv + (size_t)b*CC*UU + d;
        float l = 0.f, o = 0.f;
#pragma unroll 5
        for (int i = 0; i < 50; ++i) {
            const int k = kh*50 + i;
            const float e = s_e[h][k];
            l += e;
            o = fmaf(e, vcol[(size_t)k*UU], o);    // coalesced across d
        }
        s_pa[kh][d] = o; s_pl[kh][d] = l;
    }
    __syncthreads();
    if (t < UU) s_o[t] = (s_pa[0][t] + s_pa[1][t]) / (s_pl[0][t] + s_pl[1][t]);
    __syncthreads();

    // phase 3: out-proj partials; thread = (u, hd-half)
    {
        const int u = t & 127, half = t >> 7;
        float acc = 0.f;
#pragma unroll 4
        for (int i = 0; i < 64; ++i) {
            const int hd = half*64 + i;
            acc = fmaf(s_o[hd], gwo[hd*UU + u], acc);  // coalesced across u
        }
        s_p3[half][u] = acc;
    }
    __syncthreads();
    if (t < UU)
        out[(size_t)bq*UU + t] = gval + s_p3[0][t] + s_p3[1][t] + gbo[t];
}

extern "C" void kernel_launch(void* const* d_in, const int* in_sizes, int n_in,
                              void* d_out, int out_size, void* d_ws, size_t ws_size,
                              hipStream_t stream)
{
    (void)in_sizes; (void)n_in; (void)out_size; (void)ws_size;
    const float* x   = (const float*)d_in[0];
    const float* wq  = (const float*)d_in[1];
    const float* bq  = (const float*)d_in[2];
    const float* wk  = (const float*)d_in[3];
    const float* bk  = (const float*)d_in[4];
    const float* wv  = (const float*)d_in[5];
    const float* bv  = (const float*)d_in[6];
    const float* wo  = (const float*)d_in[7];
    const float* bo  = (const float*)d_in[8];
    const float* pos = (const float*)d_in[9];
    const float* gwq = (const float*)d_in[10];
    const float* gbq = (const float*)d_in[11];
    const float* gwk = (const float*)d_in[12];
    const float* gbk = (const float*)d_in[13];
    const float* gwv = (const float*)d_in[14];
    const float* gbv = (const float*)d_in[15];
    const float* gwo = (const float*)d_in[16];
    const float* gbo = (const float*)d_in[17];
    float* out = (float*)d_out;
    float* ws  = (float*)d_ws;

    float* gq_ws = ws;              // [8*100*128]
    float* gk_ws = ws + 102400;
    float* gv_ws = ws + 204800;

    k1_chunk_mha<<<NB*CC, 512, 0, stream>>>(x, wq, bq, wk, bk, wv, bv, wo, bo,
        pos, gwq, gbq, gwk, gbk, gwv, gbv, out, gq_ws, gk_ws, gv_ws);
    k2_graph<<<NB*CC, 256, 0, stream>>>(gq_ws, gk_ws, gv_ws, gwo, gbo, out);
}

// Round 8
// 130.823 us; speedup vs baseline: 1.1080x; 1.0237x over previous
//
#include <hip/hip_runtime.h>

// Problem constants (fixed by setup_inputs)
#define NB  8     // batch
#define SS  500   // seq
#define UU  128   // units (also GH*GD)
#define NG  5     // ngrams per chunk
#define CC  100   // chunks = S/NG
#define FF  20    // 2*C(5,2) edge-concat feature width
#define HH  5     // per-chunk heads
#define HD  10    // HH * DK (DK=2)
#define GHH 4     // graph heads

// ht[f] = xv[EI[f]]  (interleaved pair table, compile-time indexed)
__device__ __constant__ const int EI[FF] =
    {0,1, 0,2, 0,3, 0,4, 1,2, 1,3, 1,4, 2,3, 2,4, 3,4};

// qkv projection: weights block-uniform (c) -> scalar s_load broadcasts
__device__ __forceinline__ void proj10(const float* __restrict__ w,
                                       const float* __restrict__ bias,
                                       int c, const float xv[NG], float p[HD])
{
    const float2* bs2 = (const float2*)(bias + c * HD);
#pragma unroll
    for (int d2 = 0; d2 < 5; ++d2) {
        const float2 t2 = bs2[d2];
        p[2*d2] = t2.x; p[2*d2+1] = t2.y;
    }
    const float2* w2 = (const float2*)(w + c * (FF * HD));
#pragma unroll
    for (int f = 0; f < FF; ++f) {
        const float hf = xv[EI[f]];               // compile-time index
#pragma unroll
        for (int d2 = 0; d2 < 5; ++d2) {
            const float2 t2 = w2[f*5 + d2];
            p[2*d2]   = fmaf(hf, t2.x, p[2*d2]);
            p[2*d2+1] = fmaf(hf, t2.y, p[2*d2+1]);
        }
    }
}

// ---------------------------------------------------------------------------
// K1 (R5 structure, exp2 micro-opt): per-chunk edge MHA -> g, + graph qkv.
// block = (b,c), 512 threads.  vq = tid>>7 (uniform per wave-pair), u = tid&127.
// P0: vq0 -> q (pre-scaled by 1/sqrt(2)*log2e), vq1 -> k, vq2 -> v.
// P1: thread (vq,u) attends for u over v in [vq*32, vq*32+32); s_kv address
//     is wave-uniform -> true 1-address LDS broadcast (cheapest mode).
// ---------------------------------------------------------------------------
__global__ __launch_bounds__(512, 6) void k1_chunk_mha(
    const float* __restrict__ x,   const float* __restrict__ wq,
    const float* __restrict__ bq,  const float* __restrict__ wk,
    const float* __restrict__ bk,  const float* __restrict__ wv,
    const float* __restrict__ bv,  const float* __restrict__ wo,
    const float* __restrict__ bo,  const float* __restrict__ pos,
    const float* __restrict__ gwq, const float* __restrict__ gbq,
    const float* __restrict__ gwk, const float* __restrict__ gbk,
    const float* __restrict__ gwv, const float* __restrict__ gbv,
    float* __restrict__ g_out, float* __restrict__ gq_out,
    float* __restrict__ gk_out, float* __restrict__ gv_out)
{
    const int bc  = blockIdx.x;
    const int b   = bc / CC, c = bc % CC;
    const int tid = threadIdx.x;
    const int u   = tid & 127;
    const int vq  = tid >> 7;            // 0..3, uniform per wave-pair

    __shared__ float  s_q[HD][UU];       // q pre-scaled by (1/sqrt 2)*log2e
    __shared__ float4 s_kv[HH][UU];      // (k0,k1,v0,v1) per (head, pos)
    __shared__ float  s_g[UU];
    __shared__ float  s_part[4][HH*3][UU];   // (l,o0,o1) per vq,head  (30.7 KB)
    float (*s_gr)[3][UU] = (float (*)[3][UU])s_part;  // aliased after B3

    // ---------------- P0: x load + role projection -----------------------
    float xv[NG];
    if (vq < 3) {
        const float* xb = x + (size_t)b * SS * UU + (size_t)c * NG * UU + u;
#pragma unroll
        for (int t = 0; t < NG; ++t) xv[t] = xb[t * UU];   // coalesced
    }
    if (vq == 0) {
        float p[HD];
        proj10(wq, bq, c, xv, p);
        const float C = 1.0202559313584566f;   // (1/sqrt(dk=2)) * log2(e)
#pragma unroll
        for (int i = 0; i < HD; ++i) s_q[i][u] = p[i] * C;
    } else if (vq == 1) {
        float p[HD];
        proj10(wk, bk, c, xv, p);
#pragma unroll
        for (int h = 0; h < HH; ++h) { s_kv[h][u].x = p[2*h]; s_kv[h][u].y = p[2*h+1]; }
    } else if (vq == 2) {
        float p[HD];
        proj10(wv, bv, c, xv, p);
#pragma unroll
        for (int h = 0; h < HH; ++h) { s_kv[h][u].z = p[2*h]; s_kv[h][u].w = p[2*h+1]; }
    }
    __syncthreads();                               // B1: q/k/v ready

    // ---------------- P1: attention partials over vq's 32 positions ------
    float q0[HH], q1[HH];
#pragma unroll
    for (int h = 0; h < HH; ++h) { q0[h] = s_q[2*h][u]; q1[h] = s_q[2*h+1][u]; }
    float l[HH], o0[HH], o1[HH];
#pragma unroll
    for (int h = 0; h < HH; ++h) { l[h] = 0.f; o0[h] = 0.f; o1[h] = 0.f; }
    const int base = vq * 32;                      // wave-uniform
#pragma unroll
    for (int h = 0; h < HH; ++h) {
#pragma unroll 8
        for (int i = 0; i < 32; ++i) {
            const float4 kv = s_kv[h][base + i];   // 1-addr broadcast b128
            const float s = fmaf(q0[h], kv.x, q1[h] * kv.y);
            const float e = __builtin_amdgcn_exp2f(s);   // |s| tiny: exact
            l[h] += e;
            o0[h] = fmaf(e, kv.z, o0[h]);
            o1[h] = fmaf(e, kv.w, o1[h]);
        }
    }
#pragma unroll
    for (int h = 0; h < HH; ++h) {
        s_part[vq][h*3+0][u] = l[h];
        s_part[vq][h*3+1][u] = o0[h];
        s_part[vq][h*3+2][u] = o1[h];
    }
    __syncthreads();                               // B2: partials ready

    // ---------------- epilogue (vq==0 waves only) -------------------------
    if (vq == 0) {
        float o[HD];
#pragma unroll
        for (int h = 0; h < HH; ++h) {
            float L = 0.f, O0 = 0.f, O1 = 0.f;
#pragma unroll
            for (int j = 0; j < 4; ++j) {
                L  += s_part[j][h*3+0][u];
                O0 += s_part[j][h*3+1][u];
                O1 += s_part[j][h*3+2][u];
            }
            const float inv = 1.f / L;
            o[2*h] = O0 * inv; o[2*h+1] = O1 * inv;
        }
        // out-proj + residual + leaky(0.3) + mean (wo/bo scalar-broadcast)
        const float* woc = wo + c * (HD * FF);
        const float* boc = bo + c * FF;
        float gsum = 0.f;
#pragma unroll
        for (int f = 0; f < FF; ++f) {
            float acc = boc[f];
#pragma unroll
            for (int hd = 0; hd < HD; ++hd) acc = fmaf(o[hd], woc[hd*FF + f], acc);
            const float a = xv[EI[f]] + acc;
            gsum += (a > 0.f) ? a : 0.3f * a;
        }
        const float g = gsum * (1.f / FF) + pos[c*UU + u];
        s_g[u] = g;
        g_out[(size_t)bc*UU + u] = g;
    }
    __syncthreads();                               // B3: s_g ready (frees s_part)

    // ---------------- P2: graph qkv partials; thread = (u, quarter) ------
    float aq = 0.f, ak = 0.f, av = 0.f;
#pragma unroll 4
    for (int i = 0; i < 32; ++i) {
        const int u2 = vq*32 + i;                  // wave-uniform
        const float gu = s_g[u2];                  // broadcast
        aq = fmaf(gu, gwq[u2*UU + u], aq);         // coalesced across u
        ak = fmaf(gu, gwk[u2*UU + u], ak);
        av = fmaf(gu, gwv[u2*UU + u], av);
    }
    s_gr[vq][0][u] = aq; s_gr[vq][1][u] = ak; s_gr[vq][2][u] = av;
    __syncthreads();                               // B4

    // ---------------- P3: final sums + stores -----------------------------
    if (vq < 3) {
        const float s = s_gr[0][vq][u] + s_gr[1][vq][u]
                      + s_gr[2][vq][u] + s_gr[3][vq][u];
        if (vq == 0)
            gq_out[(size_t)bc*UU + u] = (s + gbq[u]) * 0.17677669529663687f;
        else if (vq == 1)
            gk_out[(size_t)bc*UU + u] = s + gbk[u];
        else
            gv_out[(size_t)bc*UU + u] = s + gbv[u];
    }
}

// ---------------------------------------------------------------------------
// K2 (R5 structure, exp2 micro-opt): graph attention + out-proj + residual.
// block=(b,q), 800 blocks x 256 threads.
// ---------------------------------------------------------------------------
__global__ __launch_bounds__(256) void k2_graph(
    const float* __restrict__ gq, const float* __restrict__ gk,
    const float* __restrict__ gv, const float* __restrict__ gwo,
    const float* __restrict__ gbo, float* __restrict__ out)
{
    const int bq = blockIdx.x;
    const int b  = bq / CC;
    const int t  = threadIdx.x;

    __shared__ float s_q[UU];
    __shared__ float s_e[GHH][CC];
    __shared__ float s_pa[2][UU];   // o partials
    __shared__ float s_pl[2][UU];   // l partials
    __shared__ float s_o[UU];
    __shared__ float s_p3[2][UU];

    float gval = 0.f;
    if (t < UU) {
        gval  = out[(size_t)bq*UU + t];            // g (written by K1)
        s_q[t] = gq[(size_t)bq*UU + t] * 1.4426950408889634f;  // fold log2e
    }
    __syncthreads();

    // phase 1: scores+exp2; thread = (k, head-pair)
    if (t < 200) {
        const int k  = (t < 100) ? t : t - 100;
        const int h0 = (t < 100) ? 0 : 2;
        const float4* krow = (const float4*)(gk + ((size_t)b*CC + k)*UU);
        const float4* q4   = (const float4*)s_q;   // uniform -> broadcast
#pragma unroll
        for (int hh = 0; hh < 2; ++hh) {
            const int h = h0 + hh;
            float s = 0.f;
#pragma unroll
            for (int i = 0; i < 8; ++i) {
                const float4 kf = krow[h*8 + i];
                const float4 qf = q4[h*8 + i];
                s = fmaf(qf.x, kf.x, s); s = fmaf(qf.y, kf.y, s);
                s = fmaf(qf.z, kf.z, s); s = fmaf(qf.w, kf.w, s);
            }
            s_e[h][k] = __builtin_amdgcn_exp2f(s); // scores tiny: shift-free
        }
    }
    __syncthreads();

    // phase 2: o/l partials; thread = (d, k-half)
    {
        const int d = t & 127, kh = t >> 7, h = d >> 5;
        const float* vcol = gv + (size_t)b*CC*UU + d;
        float l = 0.f, o = 0.f;
#pragma unroll 5
        for (int i = 0; i < 50; ++i) {
            const int k = kh*50 + i;
            const float e = s_e[h][k];
            l += e;
            o = fmaf(e, vcol[(size_t)k*UU], o);    // coalesced across d
        }
        s_pa[kh][d] = o; s_pl[kh][d] = l;
    }
    __syncthreads();
    if (t < UU) s_o[t] = (s_pa[0][t] + s_pa[1][t]) / (s_pl[0][t] + s_pl[1][t]);
    __syncthreads();

    // phase 3: out-proj partials; thread = (u, hd-half)
    {
        const int u = t & 127, half = t >> 7;
        float acc = 0.f;
#pragma unroll 4
        for (int i = 0; i < 64; ++i) {
            const int hd = half*64 + i;
            acc = fmaf(s_o[hd], gwo[hd*UU + u], acc);  // coalesced across u
        }
        s_p3[half][u] = acc;
    }
    __syncthreads();
    if (t < UU)
        out[(size_t)bq*UU + t] = gval + s_p3[0][t] + s_p3[1][t] + gbo[t];
}

extern "C" void kernel_launch(void* const* d_in, const int* in_sizes, int n_in,
                              void* d_out, int out_size, void* d_ws, size_t ws_size,
                              hipStream_t stream)
{
    (void)in_sizes; (void)n_in; (void)out_size; (void)ws_size;
    const float* x   = (const float*)d_in[0];
    const float* wq  = (const float*)d_in[1];
    const float* bq  = (const float*)d_in[2];
    const float* wk  = (const float*)d_in[3];
    const float* bk  = (const float*)d_in[4];
    const float* wv  = (const float*)d_in[5];
    const float* bv  = (const float*)d_in[6];
    const float* wo  = (const float*)d_in[7];
    const float* bo  = (const float*)d_in[8];
    const float* pos = (const float*)d_in[9];
    const float* gwq = (const float*)d_in[10];
    const float* gbq = (const float*)d_in[11];
    const float* gwk = (const float*)d_in[12];
    const float* gbk = (const float*)d_in[13];
    const float* gwv = (const float*)d_in[14];
    const float* gbv = (const float*)d_in[15];
    const float* gwo = (const float*)d_in[16];
    const float* gbo = (const float*)d_in[17];
    float* out = (float*)d_out;
    float* ws  = (float*)d_ws;

    float* gq_ws = ws;              // [8*100*128]
    float* gk_ws = ws + 102400;
    float* gv_ws = ws + 204800;

    k1_chunk_mha<<<NB*CC, 512, 0, stream>>>(x, wq, bq, wk, bk, wv, bv, wo, bo,
        pos, gwq, gbq, gwk, gbk, gwv, gbv, out, gq_ws, gk_ws, gv_ws);
    k2_graph<<<NB*CC, 256, 0, stream>>>(gq_ws, gk_ws, gv_ws, gwo, gbo, out);
}